// Round 6
// baseline (338.373 us; speedup 1.0000x reference)
//
#include <hip/hip_runtime.h>
#include <hip/hip_bf16.h>

#define DEVI __device__ __forceinline__

constexpr int kS  = 2048;
constexpr int kH  = 1024;
constexpr int kD  = 64;
constexpr int kBS = 4096;            // B*S
constexpr int kHeadEls = kS * kD;    // elements per (b,head) chunk

typedef __attribute__((ext_vector_type(4))) float f32x4;
typedef __attribute__((ext_vector_type(8))) __bf16 bf16x8;
typedef __attribute__((ext_vector_type(8))) unsigned short u16x8;
typedef __attribute__((ext_vector_type(2))) unsigned int u32x2;

DEVI unsigned short f2bf(float f) {            // RNE fp32 -> bf16
  unsigned int u = __builtin_bit_cast(unsigned int, f);
  u = u + 0x7FFFu + ((u >> 16) & 1u);
  return (unsigned short)(u >> 16);
}
DEVI float fast_exp2(float x) { float r; asm("v_exp_f32 %0, %1" : "=v"(r) : "v"(x)); return r; }
DEVI unsigned int cvt_pk(float lo, float hi) {
  unsigned int r; asm("v_cvt_pk_bf16_f32 %0, %1, %2" : "=v"(r) : "v"(lo), "v"(hi)); return r;
}
DEVI bf16x8 cvt8(const f32x4 a, const f32x4 b) {
  union { unsigned int u[4]; bf16x8 v; } r;
  r.u[0] = cvt_pk(a[0], a[1]); r.u[1] = cvt_pk(a[2], a[3]);
  r.u[2] = cvt_pk(b[0], b[1]); r.u[3] = cvt_pk(b[2], b[3]);
  return r.v;
}

#define GLDS16(g, l) __builtin_amdgcn_global_load_lds( \
    (const __attribute__((address_space(1))) void*)(g), \
    (__attribute__((address_space(3))) void*)(l), 16, 0, 0)

// ---------------------------------------------------------------------------
// fp32 -> bf16 pre-convert: q,k,v (4M els each) and Wq,Wk,Wv (1M each) into
// the AW-region stash (AW is only written later by attn_fused pass 2).
// ---------------------------------------------------------------------------
__global__ __launch_bounds__(256) void cvt_all(
    const float* __restrict__ q, const float* __restrict__ k, const float* __restrict__ v,
    const float* __restrict__ Wq, const float* __restrict__ Wk, const float* __restrict__ Wv,
    unsigned short* __restrict__ stash)
{
  const int z = blockIdx.y, x = blockIdx.x;
  const float* s;
  unsigned short* d;
  size_t i;
  if (x < 2048) {
    s = z == 0 ? q : z == 1 ? k : v;
    d = stash + (size_t)z * 4194304;
    i = ((size_t)x * 256 + threadIdx.x) * 8;
  } else {
    s = z == 0 ? Wq : z == 1 ? Wk : Wv;
    d = stash + (size_t)12582912 + (size_t)z * 1048576;
    i = ((size_t)(x - 2048) * 256 + threadIdx.x) * 8;
  }
  f32x4 a = *(const f32x4*)(s + i);
  f32x4 b = *(const f32x4*)(s + i + 4);
  union { unsigned int u[4]; u16x8 v; } r;
  r.u[0] = cvt_pk(a[0], a[1]); r.u[1] = cvt_pk(a[2], a[3]);
  r.u[2] = cvt_pk(b[0], b[1]); r.u[3] = cvt_pk(b[2], b[3]);
  *(u16x8*)(d + i) = r.v;
}

// ---------------------------------------------------------------------------
// GEMM: C[m,n] = sum_k A[m,k]*B[n,k]  (C = A @ B^T), M=4096 N=1024 K=1024.
// 2-phase double-buffered global_load_lds staging. A always bf16.
// PROJ: B bf16, C bf16 (z==2 -> transposed VPT layout).
// !PROJ: B fp32 (Wo, cvt inline), C fp32 nontemporal.
// ---------------------------------------------------------------------------
template<bool PROJ>
__global__ __launch_bounds__(256, 3) void gemm_k(
    const unsigned short* __restrict__ Aq, const unsigned short* __restrict__ Ak,
    const unsigned short* __restrict__ Av,
    const void* __restrict__ Bq, const void* __restrict__ Bk, const void* __restrict__ Bv,
    void* __restrict__ Cq, void* __restrict__ Ck, void* __restrict__ Cv)
{
  constexpr int K = kH;
  __shared__ __align__(16) unsigned char As[2][8192];
  __shared__ __align__(16) unsigned char Bs[2][PROJ ? 8192 : 16384];

  const int z = PROJ ? blockIdx.z : 0;
  const unsigned short* Ap = z == 0 ? Aq : z == 1 ? Ak : Av;
  const void* Bp = z == 0 ? Bq : z == 1 ? Bk : Bv;
  void*       Cp = z == 0 ? Cq : z == 1 ? Ck : Cv;

  const int tid  = threadIdx.x;
  const int lane = tid & 63, wv = tid >> 6;
  const int l15  = lane & 15, lg = lane >> 4;
  const int m0 = blockIdx.y * 128, n0 = blockIdx.x * 128;
  const int wM = (wv & 1) * 64, wN = (wv >> 1) * 64;

  const char* aSrc[2];
#pragma unroll
  for (int c = 0; c < 2; ++c) {
    const int row = c * 64 + (tid >> 2);
    const int cb  = ((tid & 3) * 16) ^ (((row >> 1) & 3) << 4);
    aSrc[c] = (const char*)Ap + ((size_t)(m0 + row) * K) * 2 + cb;
  }
  const char* bSrc[PROJ ? 2 : 4];
  if constexpr (PROJ) {
#pragma unroll
    for (int c = 0; c < 2; ++c) {
      const int row = c * 64 + (tid >> 2);
      const int cb  = ((tid & 3) * 16) ^ (((row >> 1) & 3) << 4);
      bSrc[c] = (const char*)Bp + ((size_t)(n0 + row) * K) * 2 + cb;
    }
  } else {
#pragma unroll
    for (int c = 0; c < 4; ++c) {
      const int row = c * 32 + wv * 8 + (lane >> 3);
      const int cb  = ((lane & 7) * 16) ^ ((row & 7) << 4);
      bSrc[c] = (const char*)Bp + ((size_t)(n0 + row) * K) * 4 + cb;
    }
  }

  int aoff[4], boff[4];
#pragma unroll
  for (int t = 0; t < 4; ++t) {
    const int rA = wM + t * 16 + l15;
    aoff[t] = rA * 64 + ((lg * 16) ^ (((rA >> 1) & 3) << 4));
    const int rB = wN + t * 16 + l15;
    boff[t] = PROJ ? (rB * 64  + ((lg * 16) ^ (((rB >> 1) & 3) << 4)))
                   : (rB * 128 + ((lg * 32) ^ ((rB & 7) << 4)));
  }

  f32x4 acc[4][4];
#pragma unroll
  for (int i = 0; i < 4; ++i)
#pragma unroll
    for (int j = 0; j < 4; ++j) acc[i][j] = {0.f, 0.f, 0.f, 0.f};

  auto STG = [&](int kk, int bb) {
#pragma unroll
    for (int c = 0; c < 2; ++c)
      GLDS16(aSrc[c] + (size_t)kk * 2, &As[bb][c * 4096 + wv * 1024]);
    if constexpr (PROJ) {
#pragma unroll
      for (int c = 0; c < 2; ++c)
        GLDS16(bSrc[c] + (size_t)kk * 2, &Bs[bb][c * 4096 + wv * 1024]);
    } else {
#pragma unroll
      for (int c = 0; c < 4; ++c)
        GLDS16(bSrc[c] + (size_t)kk * 4, &Bs[bb][c * 4096 + wv * 1024]);
    }
  };

  STG(0, 0);
  __syncthreads();
  int cur = 0;
  for (int t = 0; t < K / 32; ++t) {
    if (t < K / 32 - 1) STG((t + 1) * 32, cur ^ 1);
    bf16x8 af[4], bfr[4];
#pragma unroll
    for (int x = 0; x < 4; ++x) {
      af[x] = *(const bf16x8*)&As[cur][aoff[x]];
      if constexpr (PROJ) {
        bfr[x] = *(const bf16x8*)&Bs[cur][boff[x]];
      } else {
        f32x4 q0 = *(const f32x4*)&Bs[cur][boff[x]];
        f32x4 q1 = *(const f32x4*)&Bs[cur][boff[x] ^ 16];
        bfr[x] = cvt8(q0, q1);
      }
    }
#pragma unroll
    for (int mt = 0; mt < 4; ++mt)
#pragma unroll
      for (int nt = 0; nt < 4; ++nt)
        acc[mt][nt] = __builtin_amdgcn_mfma_f32_16x16x32_bf16(af[mt], bfr[nt], acc[mt][nt], 0, 0, 0);
    __syncthreads();   // drains next-tile staging (in flight during compute)
    cur ^= 1;
  }

  if constexpr (PROJ) {
    const bool vmode = (z == 2);
#pragma unroll
    for (int mt = 0; mt < 4; ++mt)
#pragma unroll
      for (int nt = 0; nt < 4; ++nt)
#pragma unroll
        for (int r = 0; r < 4; ++r) {
          const int row = m0 + wM + mt * 16 + lg * 4 + r;
          const int col = n0 + wN + nt * 16 + l15;
          const unsigned short hv = f2bf(acc[mt][nt][r]);
          if (!vmode) {
            ((unsigned short*)Cp)[(size_t)row * kH + col] = hv;
          } else {
            const int bn = row >> 7;                       // VPT[bn][d][j]
            const int j  = ((row & 127) << 4) | (col >> 6);
            const int d  = col & 63;
            ((unsigned short*)Cp)[(size_t)bn * kHeadEls + (size_t)d * kS + j] = hv;
          }
        }
  } else {
#pragma unroll
    for (int mt = 0; mt < 4; ++mt)
#pragma unroll
      for (int nt = 0; nt < 4; ++nt)
#pragma unroll
        for (int r = 0; r < 4; ++r) {
          const int row = m0 + wM + mt * 16 + lg * 4 + r;
          const int col = n0 + wN + nt * 16 + l15;
          __builtin_nontemporal_store(acc[mt][nt][r], (float*)Cp + (size_t)row * kH + col);
        }
  }
}

// ---------------------------------------------------------------------------
// Fused attention, one kernel, block-local dependency only.
// Block = (bn, 128 q-rows), 4 waves x 32 rows. 512 blocks, XCD-swizzled.
// Pass 1 (flash): swapped QK^T (mfma(K,Q)) -> exp -> rs + P.V; scale by 1/rs,
//   write XB. K/V LDS dbuf, XOR-swizzled; Ws P-restage (wave-private).
// Pass 2: recompute QK^T (same MFMAs -> bit-identical), write normalized AW
//   as NT dwordx4; counted vmcnt(8) + raw s_barrier so stores fly across
//   barriers (prefetch glds provably retired: in-order vmcnt, 8 newest =
//   this tile's stores).
// ---------------------------------------------------------------------------
__global__ __launch_bounds__(256, 2) void attn_fused(
    const unsigned short* __restrict__ QP,
    const unsigned short* __restrict__ KP,
    const unsigned short* __restrict__ VPT,
    float* __restrict__ AW,            // [32][2048][2048] fp32
    unsigned short* __restrict__ XB)   // [4096][1024] bf16
{
  __shared__ __align__(16) unsigned short Kb[2][4096];   // [64 j][64 d] swz
  __shared__ __align__(16) unsigned short Vb[2][4096];   // [64 d][64 j] swz
  __shared__ __align__(16) unsigned short Ws[128][64];   // P tile, swz

  const int tid  = threadIdx.x;
  const int lane = tid & 63, wv = tid >> 6;
  const int l15  = lane & 15, lg = lane >> 4;
  const int f  = blockIdx.x;
  const int bn = ((f >> 7) << 3) | (f & 7);   // 4 heads per XCD
  const int i0 = ((f >> 3) & 15) * 128;
  const int b = bn >> 4, n = bn & 15;

  const char* Khb = (const char*)(KP + (size_t)bn * kHeadEls);
  const char* Vhb = (const char*)(VPT + (size_t)bn * kHeadEls);
  const unsigned short* Qh = QP + (size_t)bn * kHeadEls;

  int kOff[2], vOff[2];
#pragma unroll
  for (int p = 0; p < 2; ++p) {
    const int sL = p * 4096 + tid * 16;
    const int srow = sL >> 7, scol = sL & 127;
    const int sw = scol ^ ((srow & 7) << 4);
    kOff[p] = srow * 128 + sw;
    vOff[p] = srow * 4096 + sw;
  }
#define STAGE_K(j0, bb) { \
    GLDS16(Khb + (size_t)(j0) * 128 + kOff[0], (char*)Kb[bb] + wv * 1024); \
    GLDS16(Khb + (size_t)(j0) * 128 + kOff[1], (char*)Kb[bb] + 4096 + wv * 1024); }
#define STAGE_V(j0, bb) { \
    GLDS16(Vhb + (size_t)(j0) * 2 + vOff[0], (char*)Vb[bb] + wv * 1024); \
    GLDS16(Vhb + (size_t)(j0) * 2 + vOff[1], (char*)Vb[bb] + 4096 + wv * 1024); }

  int koff[4][2], voff2[2][4], wswr[2][4], wsrd[2][2];
#pragma unroll
  for (int ct = 0; ct < 4; ++ct) {
    const int rK = ct * 16 + l15;
#pragma unroll
    for (int h = 0; h < 2; ++h)
      koff[ct][h] = rK * 128 + ((h * 64 + lg * 16) ^ ((rK & 7) << 4));
  }
#pragma unroll
  for (int jc = 0; jc < 2; ++jc)
#pragma unroll
    for (int dt = 0; dt < 4; ++dt) {
      const int d = dt * 16 + l15;
      voff2[jc][dt] = d * 128 + ((jc * 64 + lg * 16) ^ ((d & 7) << 4));
    }
#pragma unroll
  for (int m = 0; m < 2; ++m) {
    const int rw = wv * 32 + m * 16 + l15;
#pragma unroll
    for (int ct = 0; ct < 4; ++ct)
      wswr[m][ct] = rw * 128 + ((ct * 32 + lg * 8) ^ ((rw & 7) << 4));
#pragma unroll
    for (int jc = 0; jc < 2; ++jc)
      wsrd[m][jc] = rw * 128 + ((jc * 64 + lg * 16) ^ ((rw & 7) << 4));
  }

  bf16x8 qf[2][2];
#pragma unroll
  for (int m = 0; m < 2; ++m) {
    const int qr = i0 + wv * 32 + m * 16 + l15;
#pragma unroll
    for (int h = 0; h < 2; ++h)
      qf[m][h] = *(const bf16x8*)(Qh + (size_t)qr * kD + h * 32 + lg * 8);
  }
  const float cexp = 0.18033688011112042f;   // log2(e)/8

  // ================= pass 1: flash (rs + P.V) =================
  float rs[2] = {0.f, 0.f};
  f32x4 pv[2][4];
#pragma unroll
  for (int m = 0; m < 2; ++m)
#pragma unroll
    for (int dt = 0; dt < 4; ++dt) pv[m][dt] = {0.f, 0.f, 0.f, 0.f};

  STAGE_K(0, 0); STAGE_V(0, 0);
  __syncthreads();
  int cur = 0;
  for (int j0 = 0; j0 < kS; j0 += 64) {
    if (j0 + 64 < kS) { STAGE_K(j0 + 64, cur ^ 1); STAGE_V(j0 + 64, cur ^ 1); }
    // swapped QK^T: C col = q-row (l15), rows = 4 consecutive j (lg*4+r)
#pragma unroll
    for (int ct = 0; ct < 4; ++ct) {
      const bf16x8 kb0 = *(const bf16x8*)((const char*)Kb[cur] + koff[ct][0]);
      const bf16x8 kb1 = *(const bf16x8*)((const char*)Kb[cur] + koff[ct][1]);
#pragma unroll
      for (int m = 0; m < 2; ++m) {
        f32x4 s = {0.f, 0.f, 0.f, 0.f};
        s = __builtin_amdgcn_mfma_f32_16x16x32_bf16(kb0, qf[m][0], s, 0, 0, 0);
        s = __builtin_amdgcn_mfma_f32_16x16x32_bf16(kb1, qf[m][1], s, 0, 0, 0);
        const float w0 = fast_exp2(s[0] * cexp), w1 = fast_exp2(s[1] * cexp);
        const float w2 = fast_exp2(s[2] * cexp), w3 = fast_exp2(s[3] * cexp);
        rs[m] += (w0 + w1) + (w2 + w3);
        u32x2 pk; pk[0] = cvt_pk(w0, w1); pk[1] = cvt_pk(w2, w3);
        *(u32x2*)((char*)Ws + wswr[m][ct]) = pk;   // wave-private rows
      }
    }
    // P.V (same-wave Ws dependency; no barrier needed)
#pragma unroll
    for (int jc = 0; jc < 2; ++jc) {
      const bf16x8 pa0 = *(const bf16x8*)((const char*)Ws + wsrd[0][jc]);
      const bf16x8 pa1 = *(const bf16x8*)((const char*)Ws + wsrd[1][jc]);
#pragma unroll
      for (int dt = 0; dt < 4; ++dt) {
        const bf16x8 vf = *(const bf16x8*)((const char*)Vb[cur] + voff2[jc][dt]);
        pv[0][dt] = __builtin_amdgcn_mfma_f32_16x16x32_bf16(pa0, vf, pv[0][dt], 0, 0, 0);
        pv[1][dt] = __builtin_amdgcn_mfma_f32_16x16x32_bf16(pa1, vf, pv[1][dt], 0, 0, 0);
      }
    }
    __syncthreads();
    cur ^= 1;
  }

  // full row sums (reduce over lg groups; all lanes get their l15 row's sum)
#pragma unroll
  for (int m = 0; m < 2; ++m) {
    rs[m] += __shfl_xor(rs[m], 16, 64);
    rs[m] += __shfl_xor(rs[m], 32, 64);
  }
  float iv[2][4];
#pragma unroll
  for (int m = 0; m < 2; ++m)
#pragma unroll
    for (int r = 0; r < 4; ++r)
      iv[m][r] = 1.0f / __shfl(rs[m], lg * 4 + r, 64);

  // prefetch pass-2 K tile 0 BEFORE the XB stores (vmcnt(32) below retires it)
  STAGE_K(0, 0);

  // XB epilogue (32 scalar stores)
#pragma unroll
  for (int m = 0; m < 2; ++m)
#pragma unroll
    for (int dt = 0; dt < 4; ++dt)
#pragma unroll
      for (int r = 0; r < 4; ++r) {
        const int row = b * kS + i0 + wv * 32 + m * 16 + lg * 4 + r;  // (b,i)
        const int col = n * 64 + dt * 16 + l15;                       // (n d)
        XB[(size_t)row * kH + col] = f2bf(pv[m][dt][r] * iv[m][r]);
      }

  // ================= pass 2: AW writer =================
  const float ivm0 = 1.0f / rs[0], ivm1 = 1.0f / rs[1];
  float* awr0 = AW + ((size_t)(bn * kS + i0 + wv * 32 + l15)) * kS + lg * 4;
  float* awr1 = awr0 + (size_t)16 * kS;

  asm volatile("s_waitcnt vmcnt(32)" ::: "memory");   // glds retired; XB stores fly
  __builtin_amdgcn_sched_barrier(0);
  __builtin_amdgcn_s_barrier();
  cur = 0;
  for (int t = 0; t < 32; ++t) {
    const int j0 = t * 64;
    if (t < 31) STAGE_K(j0 + 64, cur ^ 1);
#pragma unroll
    for (int ct = 0; ct < 4; ++ct) {
      const bf16x8 kb0 = *(const bf16x8*)((const char*)Kb[cur] + koff[ct][0]);
      const bf16x8 kb1 = *(const bf16x8*)((const char*)Kb[cur] + koff[ct][1]);
      {
        f32x4 s = {0.f, 0.f, 0.f, 0.f};
        s = __builtin_amdgcn_mfma_f32_16x16x32_bf16(kb0, qf[0][0], s, 0, 0, 0);
        s = __builtin_amdgcn_mfma_f32_16x16x32_bf16(kb1, qf[0][1], s, 0, 0, 0);
        f32x4 w;
#pragma unroll
        for (int r = 0; r < 4; ++r) w[r] = fast_exp2(s[r] * cexp) * ivm0;
        __builtin_nontemporal_store(w, (f32x4*)(awr0 + j0 + ct * 16));
      }
      {
        f32x4 s = {0.f, 0.f, 0.f, 0.f};
        s = __builtin_amdgcn_mfma_f32_16x16x32_bf16(kb0, qf[1][0], s, 0, 0, 0);
        s = __builtin_amdgcn_mfma_f32_16x16x32_bf16(kb1, qf[1][1], s, 0, 0, 0);
        f32x4 w;
#pragma unroll
        for (int r = 0; r < 4; ++r) w[r] = fast_exp2(s[r] * cexp) * ivm1;
        __builtin_nontemporal_store(w, (f32x4*)(awr1 + j0 + ct * 16));
      }
    }
    if (t < 31) {
      // 8 newest outstanding = this tile's stores; older (prev stores +
      // next-tile glds) retired in order -> LDS safe, stores stay in flight.
      asm volatile("s_waitcnt vmcnt(8) lgkmcnt(0)" ::: "memory");
      __builtin_amdgcn_sched_barrier(0);
      __builtin_amdgcn_s_barrier();
    }
    cur ^= 1;
  }
#undef STAGE_K
#undef STAGE_V
}

// ---------------------------------------------------------------------------
extern "C" void kernel_launch(void* const* d_in, const int* in_sizes, int n_in,
                              void* d_out, int out_size, void* d_ws, size_t ws_size,
                              hipStream_t stream) {
  const float* q  = (const float*)d_in[0];
  const float* k  = (const float*)d_in[1];
  const float* v  = (const float*)d_in[2];
  const float* Wq = (const float*)d_in[3];
  const float* Wk = (const float*)d_in[4];
  const float* Wv = (const float*)d_in[5];
  const float* Wo = (const float*)d_in[6];

  float* out = (float*)d_out;
  float* aw  = out + (size_t)kBS * kH;

  unsigned short* QP  = (unsigned short*)d_ws;         // 8 MB
  unsigned short* KP  = QP  + (size_t)kBS * kH;        // 8 MB
  unsigned short* VPT = KP  + (size_t)kBS * kH;        // 8 MB
  unsigned short* XB  = VPT + (size_t)kBS * kH;        // 8 MB (total 32 MB)

  // bf16 stash in AW region: consumed by proj (disp 2) before attn writes AW
  unsigned short* stash = (unsigned short*)aw;
  unsigned short* QB  = stash;
  unsigned short* KB  = stash + (size_t)4194304;
  unsigned short* VB  = stash + (size_t)8388608;
  unsigned short* Wqb = stash + (size_t)12582912;
  unsigned short* Wkb = stash + (size_t)13631488;
  unsigned short* Wvb = stash + (size_t)14680064;

  cvt_all<<<dim3(2560, 3), 256, 0, stream>>>(q, k, v, Wq, Wk, Wv, stash);
  gemm_k<true><<<dim3(8, 32, 3), 256, 0, stream>>>(QB, KB, VB, Wqb, Wkb, Wvb, QP, KP, VPT);
  attn_fused<<<dim3(512), 256, 0, stream>>>(QP, KP, VPT, aw, XB);
  gemm_k<false><<<dim3(8, 32, 1), 256, 0, stream>>>(XB, XB, XB, Wo, Wo, Wo, out, out, out);
}

// Round 7
// 331.248 us; speedup vs baseline: 1.0215x; 1.0215x over previous
//
#include <hip/hip_runtime.h>
#include <hip/hip_bf16.h>

#define DEVI __device__ __forceinline__

constexpr int kS  = 2048;
constexpr int kH  = 1024;
constexpr int kD  = 64;
constexpr int kBS = 4096;            // B*S
constexpr int kHeadEls = kS * kD;    // elements per (b,head) chunk

typedef __attribute__((ext_vector_type(4))) float f32x4;
typedef __attribute__((ext_vector_type(8))) __bf16 bf16x8;
typedef __attribute__((ext_vector_type(8))) unsigned short u16x8;
typedef __attribute__((ext_vector_type(2))) unsigned int u32x2;

DEVI unsigned short f2bf(float f) {            // RNE fp32 -> bf16
  unsigned int u = __builtin_bit_cast(unsigned int, f);
  u = u + 0x7FFFu + ((u >> 16) & 1u);
  return (unsigned short)(u >> 16);
}
DEVI float fast_exp2(float x) { float r; asm("v_exp_f32 %0, %1" : "=v"(r) : "v"(x)); return r; }
DEVI unsigned int cvt_pk(float lo, float hi) {
  unsigned int r; asm("v_cvt_pk_bf16_f32 %0, %1, %2" : "=v"(r) : "v"(lo), "v"(hi)); return r;
}
DEVI bf16x8 cvt8(const f32x4 a, const f32x4 b) {
  union { unsigned int u[4]; bf16x8 v; } r;
  r.u[0] = cvt_pk(a[0], a[1]); r.u[1] = cvt_pk(a[2], a[3]);
  r.u[2] = cvt_pk(b[0], b[1]); r.u[3] = cvt_pk(b[2], b[3]);
  return r.v;
}

#define GLDS16(g, l) __builtin_amdgcn_global_load_lds( \
    (const __attribute__((address_space(1))) void*)(g), \
    (__attribute__((address_space(3))) void*)(l), 16, 0, 0)

// ---------------------------------------------------------------------------
// fp32 -> bf16 pre-convert: q,k,v (4M els each) and Wq,Wk,Wv (1M each) into
// the AW-region stash (AW is only written later by attn_fused pass 2).
// ---------------------------------------------------------------------------
__global__ __launch_bounds__(256) void cvt_all(
    const float* __restrict__ q, const float* __restrict__ k, const float* __restrict__ v,
    const float* __restrict__ Wq, const float* __restrict__ Wk, const float* __restrict__ Wv,
    unsigned short* __restrict__ stash)
{
  const int z = blockIdx.y, x = blockIdx.x;
  const float* s;
  unsigned short* d;
  size_t i;
  if (x < 2048) {
    s = z == 0 ? q : z == 1 ? k : v;
    d = stash + (size_t)z * 4194304;
    i = ((size_t)x * 256 + threadIdx.x) * 8;
  } else {
    s = z == 0 ? Wq : z == 1 ? Wk : Wv;
    d = stash + (size_t)12582912 + (size_t)z * 1048576;
    i = ((size_t)(x - 2048) * 256 + threadIdx.x) * 8;
  }
  f32x4 a = *(const f32x4*)(s + i);
  f32x4 b = *(const f32x4*)(s + i + 4);
  union { unsigned int u[4]; u16x8 v; } r;
  r.u[0] = cvt_pk(a[0], a[1]); r.u[1] = cvt_pk(a[2], a[3]);
  r.u[2] = cvt_pk(b[0], b[1]); r.u[3] = cvt_pk(b[2], b[3]);
  *(u16x8*)(d + i) = r.v;
}

// ---------------------------------------------------------------------------
// GEMM: C[m,n] = sum_k A[m,k]*B[n,k]  (C = A @ B^T), M=4096 N=1024 K=1024.
// 2-phase double-buffered global_load_lds staging. A always bf16.
// PROJ: B bf16, C bf16 (z==2 -> transposed VPT layout).
// !PROJ: B fp32 (Wo, cvt inline), C fp32 nontemporal.
// ---------------------------------------------------------------------------
template<bool PROJ>
__global__ __launch_bounds__(256, 3) void gemm_k(
    const unsigned short* __restrict__ Aq, const unsigned short* __restrict__ Ak,
    const unsigned short* __restrict__ Av,
    const void* __restrict__ Bq, const void* __restrict__ Bk, const void* __restrict__ Bv,
    void* __restrict__ Cq, void* __restrict__ Ck, void* __restrict__ Cv)
{
  constexpr int K = kH;
  __shared__ __align__(16) unsigned char As[2][8192];
  __shared__ __align__(16) unsigned char Bs[2][PROJ ? 8192 : 16384];

  const int z = PROJ ? blockIdx.z : 0;
  const unsigned short* Ap = z == 0 ? Aq : z == 1 ? Ak : Av;
  const void* Bp = z == 0 ? Bq : z == 1 ? Bk : Bv;
  void*       Cp = z == 0 ? Cq : z == 1 ? Ck : Cv;

  const int tid  = threadIdx.x;
  const int lane = tid & 63, wv = tid >> 6;
  const int l15  = lane & 15, lg = lane >> 4;
  const int m0 = blockIdx.y * 128, n0 = blockIdx.x * 128;
  const int wM = (wv & 1) * 64, wN = (wv >> 1) * 64;

  const char* aSrc[2];
#pragma unroll
  for (int c = 0; c < 2; ++c) {
    const int row = c * 64 + (tid >> 2);
    const int cb  = ((tid & 3) * 16) ^ (((row >> 1) & 3) << 4);
    aSrc[c] = (const char*)Ap + ((size_t)(m0 + row) * K) * 2 + cb;
  }
  const char* bSrc[PROJ ? 2 : 4];
  if constexpr (PROJ) {
#pragma unroll
    for (int c = 0; c < 2; ++c) {
      const int row = c * 64 + (tid >> 2);
      const int cb  = ((tid & 3) * 16) ^ (((row >> 1) & 3) << 4);
      bSrc[c] = (const char*)Bp + ((size_t)(n0 + row) * K) * 2 + cb;
    }
  } else {
#pragma unroll
    for (int c = 0; c < 4; ++c) {
      const int row = c * 32 + wv * 8 + (lane >> 3);
      const int cb  = ((lane & 7) * 16) ^ ((row & 7) << 4);
      bSrc[c] = (const char*)Bp + ((size_t)(n0 + row) * K) * 4 + cb;
    }
  }

  int aoff[4], boff[4];
#pragma unroll
  for (int t = 0; t < 4; ++t) {
    const int rA = wM + t * 16 + l15;
    aoff[t] = rA * 64 + ((lg * 16) ^ (((rA >> 1) & 3) << 4));
    const int rB = wN + t * 16 + l15;
    boff[t] = PROJ ? (rB * 64  + ((lg * 16) ^ (((rB >> 1) & 3) << 4)))
                   : (rB * 128 + ((lg * 32) ^ ((rB & 7) << 4)));
  }

  f32x4 acc[4][4];
#pragma unroll
  for (int i = 0; i < 4; ++i)
#pragma unroll
    for (int j = 0; j < 4; ++j) acc[i][j] = {0.f, 0.f, 0.f, 0.f};

  auto STG = [&](int kk, int bb) {
#pragma unroll
    for (int c = 0; c < 2; ++c)
      GLDS16(aSrc[c] + (size_t)kk * 2, &As[bb][c * 4096 + wv * 1024]);
    if constexpr (PROJ) {
#pragma unroll
      for (int c = 0; c < 2; ++c)
        GLDS16(bSrc[c] + (size_t)kk * 2, &Bs[bb][c * 4096 + wv * 1024]);
    } else {
#pragma unroll
      for (int c = 0; c < 4; ++c)
        GLDS16(bSrc[c] + (size_t)kk * 4, &Bs[bb][c * 4096 + wv * 1024]);
    }
  };

  STG(0, 0);
  __syncthreads();
  int cur = 0;
  for (int t = 0; t < K / 32; ++t) {
    if (t < K / 32 - 1) STG((t + 1) * 32, cur ^ 1);
    bf16x8 af[4], bfr[4];
#pragma unroll
    for (int x = 0; x < 4; ++x) {
      af[x] = *(const bf16x8*)&As[cur][aoff[x]];
      if constexpr (PROJ) {
        bfr[x] = *(const bf16x8*)&Bs[cur][boff[x]];
      } else {
        f32x4 q0 = *(const f32x4*)&Bs[cur][boff[x]];
        f32x4 q1 = *(const f32x4*)&Bs[cur][boff[x] ^ 16];
        bfr[x] = cvt8(q0, q1);
      }
    }
#pragma unroll
    for (int mt = 0; mt < 4; ++mt)
#pragma unroll
      for (int nt = 0; nt < 4; ++nt)
        acc[mt][nt] = __builtin_amdgcn_mfma_f32_16x16x32_bf16(af[mt], bfr[nt], acc[mt][nt], 0, 0, 0);
    __syncthreads();   // drains next-tile staging (in flight during compute)
    cur ^= 1;
  }

  if constexpr (PROJ) {
    const bool vmode = (z == 2);
#pragma unroll
    for (int mt = 0; mt < 4; ++mt)
#pragma unroll
      for (int nt = 0; nt < 4; ++nt)
#pragma unroll
        for (int r = 0; r < 4; ++r) {
          const int row = m0 + wM + mt * 16 + lg * 4 + r;
          const int col = n0 + wN + nt * 16 + l15;
          const unsigned short hv = f2bf(acc[mt][nt][r]);
          if (!vmode) {
            ((unsigned short*)Cp)[(size_t)row * kH + col] = hv;
          } else {
            const int bn = row >> 7;                       // VPT[bn][d][j]
            const int j  = ((row & 127) << 4) | (col >> 6);
            const int d  = col & 63;
            ((unsigned short*)Cp)[(size_t)bn * kHeadEls + (size_t)d * kS + j] = hv;
          }
        }
  } else {
#pragma unroll
    for (int mt = 0; mt < 4; ++mt)
#pragma unroll
      for (int nt = 0; nt < 4; ++nt)
#pragma unroll
        for (int r = 0; r < 4; ++r) {
          const int row = m0 + wM + mt * 16 + lg * 4 + r;
          const int col = n0 + wN + nt * 16 + l15;
          __builtin_nontemporal_store(acc[mt][nt][r], (float*)Cp + (size_t)row * kH + col);
        }
  }
}

// ---------------------------------------------------------------------------
// Fused attention. Block = (bn, 128 q-rows), 4 waves x 32 rows, 512 blocks.
// Pass 1 (flash): swapped QK^T -> exp -> rs + P.V; scale by 1/rs, write XB.
// Pass 2: recompute QK^T (bit-identical), NT-store normalized AW. K ring-8
//   LDS buffers, prefetch distance 7, counted vmcnt(52)/(48) + raw s_barrier:
//   retires only the glds needed 7 tiles ahead while ~44 NT stores/wave stay
//   in flight (deep store window -> write BW saturation).
// ---------------------------------------------------------------------------
__global__ __launch_bounds__(256, 2) void attn_fused(
    const unsigned short* __restrict__ QP,
    const unsigned short* __restrict__ KP,
    const unsigned short* __restrict__ VPT,
    float* __restrict__ AW,            // [32][2048][2048] fp32
    unsigned short* __restrict__ XB)   // [4096][1024] bf16
{
  // union LDS: pass 1 = Kb[2](16K) | Vb[2](16K) | Ws(16K);  pass 2 = 8x8K ring
  __shared__ __align__(16) unsigned char SM[65536];
  unsigned short (*Kb)[4096] = (unsigned short(*)[4096])SM;
  unsigned short (*Vb)[4096] = (unsigned short(*)[4096])(SM + 16384);
  char* Wsb = (char*)(SM + 32768);

  const int tid  = threadIdx.x;
  const int lane = tid & 63, wv = tid >> 6;
  const int l15  = lane & 15, lg = lane >> 4;
  const int f  = blockIdx.x;
  const int bn = ((f >> 7) << 3) | (f & 7);   // 4 heads per XCD
  const int i0 = ((f >> 3) & 15) * 128;
  const int b = bn >> 4, n = bn & 15;

  const char* Khb = (const char*)(KP + (size_t)bn * kHeadEls);
  const char* Vhb = (const char*)(VPT + (size_t)bn * kHeadEls);
  const unsigned short* Qh = QP + (size_t)bn * kHeadEls;

  int kOff[2], vOff[2];
#pragma unroll
  for (int p = 0; p < 2; ++p) {
    const int sL = p * 4096 + tid * 16;
    const int srow = sL >> 7, scol = sL & 127;
    const int sw = scol ^ ((srow & 7) << 4);
    kOff[p] = srow * 128 + sw;
    vOff[p] = srow * 4096 + sw;
  }
#define STAGE_K(j0, bb) { \
    GLDS16(Khb + (size_t)(j0) * 128 + kOff[0], (char*)Kb[bb] + wv * 1024); \
    GLDS16(Khb + (size_t)(j0) * 128 + kOff[1], (char*)Kb[bb] + 4096 + wv * 1024); }
#define STAGE_V(j0, bb) { \
    GLDS16(Vhb + (size_t)(j0) * 2 + vOff[0], (char*)Vb[bb] + wv * 1024); \
    GLDS16(Vhb + (size_t)(j0) * 2 + vOff[1], (char*)Vb[bb] + 4096 + wv * 1024); }
#define STAGE_P2(j0, sl) { \
    GLDS16(Khb + (size_t)(j0) * 128 + kOff[0], (char*)SM + (sl) * 8192 + wv * 1024); \
    GLDS16(Khb + (size_t)(j0) * 128 + kOff[1], (char*)SM + (sl) * 8192 + 4096 + wv * 1024); }

  int koff[4][2], voff2[2][4], wswr[2][4], wsrd[2][2];
#pragma unroll
  for (int ct = 0; ct < 4; ++ct) {
    const int rK = ct * 16 + l15;
#pragma unroll
    for (int h = 0; h < 2; ++h)
      koff[ct][h] = rK * 128 + ((h * 64 + lg * 16) ^ ((rK & 7) << 4));
  }
#pragma unroll
  for (int jc = 0; jc < 2; ++jc)
#pragma unroll
    for (int dt = 0; dt < 4; ++dt) {
      const int d = dt * 16 + l15;
      voff2[jc][dt] = d * 128 + ((jc * 64 + lg * 16) ^ ((d & 7) << 4));
    }
#pragma unroll
  for (int m = 0; m < 2; ++m) {
    const int rw = wv * 32 + m * 16 + l15;
#pragma unroll
    for (int ct = 0; ct < 4; ++ct)
      wswr[m][ct] = rw * 128 + ((ct * 32 + lg * 8) ^ ((rw & 7) << 4));
#pragma unroll
    for (int jc = 0; jc < 2; ++jc)
      wsrd[m][jc] = rw * 128 + ((jc * 64 + lg * 16) ^ ((rw & 7) << 4));
  }

  bf16x8 qf[2][2];
#pragma unroll
  for (int m = 0; m < 2; ++m) {
    const int qr = i0 + wv * 32 + m * 16 + l15;
#pragma unroll
    for (int h = 0; h < 2; ++h)
      qf[m][h] = *(const bf16x8*)(Qh + (size_t)qr * kD + h * 32 + lg * 8);
  }
  const float cexp = 0.18033688011112042f;   // log2(e)/8

  // ================= pass 1: flash (rs + P.V) =================
  float rs[2] = {0.f, 0.f};
  f32x4 pv[2][4];
#pragma unroll
  for (int m = 0; m < 2; ++m)
#pragma unroll
    for (int dt = 0; dt < 4; ++dt) pv[m][dt] = {0.f, 0.f, 0.f, 0.f};

  STAGE_K(0, 0); STAGE_V(0, 0);
  __syncthreads();
  int cur = 0;
  for (int j0 = 0; j0 < kS; j0 += 64) {
    if (j0 + 64 < kS) { STAGE_K(j0 + 64, cur ^ 1); STAGE_V(j0 + 64, cur ^ 1); }
    // swapped QK^T: C col = q-row (l15), rows = 4 consecutive j (lg*4+r)
#pragma unroll
    for (int ct = 0; ct < 4; ++ct) {
      const bf16x8 kb0 = *(const bf16x8*)((const char*)Kb[cur] + koff[ct][0]);
      const bf16x8 kb1 = *(const bf16x8*)((const char*)Kb[cur] + koff[ct][1]);
#pragma unroll
      for (int m = 0; m < 2; ++m) {
        f32x4 s = {0.f, 0.f, 0.f, 0.f};
        s = __builtin_amdgcn_mfma_f32_16x16x32_bf16(kb0, qf[m][0], s, 0, 0, 0);
        s = __builtin_amdgcn_mfma_f32_16x16x32_bf16(kb1, qf[m][1], s, 0, 0, 0);
        const float w0 = fast_exp2(s[0] * cexp), w1 = fast_exp2(s[1] * cexp);
        const float w2 = fast_exp2(s[2] * cexp), w3 = fast_exp2(s[3] * cexp);
        rs[m] += (w0 + w1) + (w2 + w3);
        u32x2 pk; pk[0] = cvt_pk(w0, w1); pk[1] = cvt_pk(w2, w3);
        *(u32x2*)(Wsb + wswr[m][ct]) = pk;   // wave-private rows
      }
    }
    // P.V (same-wave Ws dependency; no barrier needed)
#pragma unroll
    for (int jc = 0; jc < 2; ++jc) {
      const bf16x8 pa0 = *(const bf16x8*)(Wsb + wsrd[0][jc]);
      const bf16x8 pa1 = *(const bf16x8*)(Wsb + wsrd[1][jc]);
#pragma unroll
      for (int dt = 0; dt < 4; ++dt) {
        const bf16x8 vf = *(const bf16x8*)((const char*)Vb[cur] + voff2[jc][dt]);
        pv[0][dt] = __builtin_amdgcn_mfma_f32_16x16x32_bf16(pa0, vf, pv[0][dt], 0, 0, 0);
        pv[1][dt] = __builtin_amdgcn_mfma_f32_16x16x32_bf16(pa1, vf, pv[1][dt], 0, 0, 0);
      }
    }
    __syncthreads();
    cur ^= 1;
  }

  // full row sums (reduce over lg groups; all lanes get their l15 row's sum)
#pragma unroll
  for (int m = 0; m < 2; ++m) {
    rs[m] += __shfl_xor(rs[m], 16, 64);
    rs[m] += __shfl_xor(rs[m], 32, 64);
  }
  float iv[2][4];
#pragma unroll
  for (int m = 0; m < 2; ++m)
#pragma unroll
    for (int r = 0; r < 4; ++r)
      iv[m][r] = 1.0f / __shfl(rs[m], lg * 4 + r, 64);

  // ================= pass 2 prologue =================
  // stage tiles 0..6 into ring slots 0..6 BEFORE the XB stores; vmcnt(32)
  // below retires all 14 glds (they are older than the 32 XB stores).
#pragma unroll
  for (int u = 0; u < 7; ++u) STAGE_P2(u * 64, u);
  __builtin_amdgcn_sched_barrier(0);   // pin glds before XB stores

#pragma unroll
  for (int m = 0; m < 2; ++m)
#pragma unroll
    for (int dt = 0; dt < 4; ++dt)
#pragma unroll
      for (int r = 0; r < 4; ++r) {
        const int row = b * kS + i0 + wv * 32 + m * 16 + lg * 4 + r;  // (b,i)
        const int col = n * 64 + dt * 16 + l15;                       // (n d)
        XB[(size_t)row * kH + col] = f2bf(pv[m][dt][r] * iv[m][r]);
      }

  const float ivm0 = 1.0f / rs[0], ivm1 = 1.0f / rs[1];
  float* awr0 = AW + ((size_t)(bn * kS + i0 + wv * 32 + l15)) * kS + lg * 4;
  float* awr1 = awr0 + (size_t)16 * kS;

  asm volatile("s_waitcnt vmcnt(32) lgkmcnt(0)" ::: "memory");
  __builtin_amdgcn_sched_barrier(0);
  __builtin_amdgcn_s_barrier();

  // ================= pass 2 main loop: ring-8, window-6 =================
  int slot = 0, sslot = 7;
  for (int t = 0; t < 32; ++t) {
    const char* kb = (const char*)SM + slot * 8192;
#pragma unroll
    for (int ct = 0; ct < 4; ++ct) {
      const bf16x8 kb0 = *(const bf16x8*)(kb + koff[ct][0]);
      const bf16x8 kb1 = *(const bf16x8*)(kb + koff[ct][1]);
      {
        f32x4 s = {0.f, 0.f, 0.f, 0.f};
        s = __builtin_amdgcn_mfma_f32_16x16x32_bf16(kb0, qf[0][0], s, 0, 0, 0);
        s = __builtin_amdgcn_mfma_f32_16x16x32_bf16(kb1, qf[0][1], s, 0, 0, 0);
        f32x4 w;
#pragma unroll
        for (int r = 0; r < 4; ++r) w[r] = fast_exp2(s[r] * cexp) * ivm0;
        __builtin_nontemporal_store(w, (f32x4*)(awr0 + t * 64 + ct * 16));
      }
      {
        f32x4 s = {0.f, 0.f, 0.f, 0.f};
        s = __builtin_amdgcn_mfma_f32_16x16x32_bf16(kb0, qf[1][0], s, 0, 0, 0);
        s = __builtin_amdgcn_mfma_f32_16x16x32_bf16(kb1, qf[1][1], s, 0, 0, 0);
        f32x4 w;
#pragma unroll
        for (int r = 0; r < 4; ++r) w[r] = fast_exp2(s[r] * cexp) * ivm1;
        __builtin_nontemporal_store(w, (f32x4*)(awr1 + t * 64 + ct * 16));
      }
    }
    __builtin_amdgcn_sched_barrier(0);   // pin this tile's stores before glds
    if (t < 25) STAGE_P2((t + 7) * 64, sslot);
    if (t < 31) {
      // retire glds(t+1) (issued 7 tiles back): ops newer than it = 6x8
      // stores + 6x2 glds = 60 >= 52. Keep ~44 NT stores in flight/wave.
      if (t < 25) { asm volatile("s_waitcnt vmcnt(52) lgkmcnt(0)" ::: "memory"); }
      else        { asm volatile("s_waitcnt vmcnt(48) lgkmcnt(0)" ::: "memory"); }
      __builtin_amdgcn_sched_barrier(0);
      __builtin_amdgcn_s_barrier();
    }
    slot  = slot  == 7 ? 0 : slot + 1;
    sslot = sslot == 7 ? 0 : sslot + 1;
  }
#undef STAGE_K
#undef STAGE_V
#undef STAGE_P2
}

// ---------------------------------------------------------------------------
extern "C" void kernel_launch(void* const* d_in, const int* in_sizes, int n_in,
                              void* d_out, int out_size, void* d_ws, size_t ws_size,
                              hipStream_t stream) {
  const float* q  = (const float*)d_in[0];
  const float* k  = (const float*)d_in[1];
  const float* v  = (const float*)d_in[2];
  const float* Wq = (const float*)d_in[3];
  const float* Wk = (const float*)d_in[4];
  const float* Wv = (const float*)d_in[5];
  const float* Wo = (const float*)d_in[6];

  float* out = (float*)d_out;
  float* aw  = out + (size_t)kBS * kH;

  unsigned short* QP  = (unsigned short*)d_ws;         // 8 MB
  unsigned short* KP  = QP  + (size_t)kBS * kH;        // 8 MB
  unsigned short* VPT = KP  + (size_t)kBS * kH;        // 8 MB
  unsigned short* XB  = VPT + (size_t)kBS * kH;        // 8 MB (total 32 MB)

  // bf16 stash in AW region: consumed by proj (disp 2) before attn writes AW
  unsigned short* stash = (unsigned short*)aw;
  unsigned short* QB  = stash;
  unsigned short* KB  = stash + (size_t)4194304;
  unsigned short* VB  = stash + (size_t)8388608;
  unsigned short* Wqb = stash + (size_t)12582912;
  unsigned short* Wkb = stash + (size_t)13631488;
  unsigned short* Wvb = stash + (size_t)14680064;

  cvt_all<<<dim3(2560, 3), 256, 0, stream>>>(q, k, v, Wq, Wk, Wv, stash);
  gemm_k<true><<<dim3(8, 32, 3), 256, 0, stream>>>(QB, KB, VB, Wqb, Wkb, Wvb, QP, KP, VPT);
  attn_fused<<<dim3(512), 256, 0, stream>>>(QP, KP, VPT, aw, XB);
  gemm_k<false><<<dim3(8, 32, 1), 256, 0, stream>>>(XB, XB, XB, Wo, Wo, Wo, out, out, out);
}